// Round 2
// baseline (129.078 us; speedup 1.0000x reference)
//
#include <hip/hip_runtime.h>

#define T      64
#define S      32
#define NGRAPH 64
#define NSPLIT 8      // slices per graph -> 512 blocks of 256 (2 blocks/CU)
#define NW     4
#define TRASH  32     // row 32 is never read (valid delta rows are 1..31)

// Delta-encoded ECT with TRANSPOSED bins: bins[c*256 + tid] so the LDS bank
// (= tid mod 32) is independent of the data-dependent slot c (conflict-free
// by construction; 2 lanes/bank = free).
//
// R13 change: the 3-slot delta scatter was a ds_read -> v_add -> ds_write
// RMW with data-dependent addresses. The compiler can't disprove aliasing
// across iterations, so DS ops stayed ordered and every iteration paid a
// waited LDS round-trip (lgkmcnt(0) drains, shared with the x[] s_loads).
// Each thread owns its private column, so the RMW needs no atomicity -- but
// atomicAdd on LDS lowers to no-return ds_add_f32: one fire-and-forget pipe
// op, nothing in the loop ever waits on DS. DS ops 6->3/node, no lgkm
// dependency chain, unroll 4 keeps 12 s_loads in flight.
//
// Numerics (R9/R10-validated, absmax 4.0): per (node,theta) profile is
// 0..0, sm, s0, ~1..1; 3 deltas at slots ss-1, ss, ss+1 (third ~ 1-s0v,
// err <= 8.2e-4); slots <= 0 fold into base register; slots >= 32 -> trash.
// Per-thread add order is unchanged (in-order DS pipe) -> bitwise-identical
// accumulation per column.
__global__ __launch_bounds__(256, 2) void ect_partial(
    const float* __restrict__ x, const float* __restrict__ v,
    const float* __restrict__ lin, const int* __restrict__ batch,
    float* __restrict__ ws, int n_points)
{
    __shared__ float bins[33 * 256]; // [c][tid]: c=0 base, 1..31 deltas, 32 trash

    const int tid  = threadIdx.x;
    const int t    = tid & 63;       // lane == theta
    const int w    = __builtin_amdgcn_readfirstlane(tid >> 6); // wave id, SGPR
    const int b    = blockIdx.x;
    const int g    = b >> 3;         // graph
    const int c    = b & (NSPLIT - 1);

    {   // vectorized zero-init of live rows 0..31: 2048 float4, 8 per thread
        const float4 z4 = {0.0f, 0.0f, 0.0f, 0.0f};
        float4* b4 = (float4*)bins;
#pragma unroll
        for (int i = 0; i < 8; i++) b4[tid + i * 256] = z4;
        // trash row 32 left uninitialized: receives adds, never read
    }

    // 32-ary ballot search (lanes<32: lower_bound(g), >=32: lower_bound(g+1))
    const int target = (t < 32) ? g : (g + 1);
    const int i32    = t & 31;
    int lo = 0;
    const int strides[3] = {2048, 64, 2};
#pragma unroll
    for (int rnd = 0; rnd < 3; rnd++) {
        const int stride = strides[rnd];
        const int idx  = lo + i32 * stride;
        const int pv   = batch[min(idx, n_points - 1)];
        const bool prd = (idx < n_points) && (pv < target);
        const unsigned long long bal = __ballot(prd);
        const int cnt = __popc((unsigned)(bal >> (t & 32)));
        lo += max(cnt - 1, 0) * stride;
    }
    if ((lo < n_points) && (batch[min(lo, n_points - 1)] < target)) lo++;
    const int gstart = __builtin_amdgcn_readfirstlane(lo);
    const int gend   = __builtin_amdgcn_readlane(lo, 32);
    const int len    = gend - gstart;
    const int n0     = gstart + (len * c) / NSPLIT;
    const int n1     = gstart + (len * (c + 1)) / NSPLIT;

    const float lin0     = lin[0];
    const float step     = lin[1] - lin0;
    const float inv_step = 1.0f / step;
    const float nl0i     = -lin0 * inv_step;
    const float K2 = (100.0f * step) * 1.4426950408889634f;   // ~10.24
    const float r  = __builtin_amdgcn_exp2f(-K2);

    const float v0 = v[0 * T + t];
    const float v1 = v[1 * T + t];
    const float v2 = v[2 * T + t];

    float v0acc = 0.0f;                 // profile value at s=0
    __syncthreads();

#pragma unroll 4
    for (int n = n0 + w; n < n1; n += NW) {     // n wave-uniform -> s_loads
        const float x0 = x[3 * n + 0];
        const float x1 = x[3 * n + 1];
        const float x2 = x[3 * n + 2];
        const float nh = fmaf(x0, v0, fmaf(x1, v1, x2 * v2));
        const float f  = fmaf(nh, inv_step, nl0i);
        const float fs = ceilf(f);
        const int   ss = (int)fs;
        const float e0 = __builtin_amdgcn_exp2f(fmaf(K2, f - fs, K2)); // (1,e^d]
        const float e1 = e0 * r;                                        // (r,1]
        const float sm  = __builtin_amdgcn_rcpf(1.0f + e0);
        const float s0v = __builtin_amdgcn_rcpf(1.0f + e1);
        v0acc += (ss <= -1) ? 1.0f : (ss == 0 ? s0v : (ss == 1 ? sm : 0.0f));
        // deltas at slots ss-1, ss, ss+1; in-range [1,31] else trash (32)
        const int p0 = ss - 1, p1 = ss, p2 = ss + 1;
        const int a0 = (((unsigned)(p0 - 1) < 31u) ? p0 : TRASH) * 256 + tid;
        const int a1 = (((unsigned)(p1 - 1) < 31u) ? p1 : TRASH) * 256 + tid;
        const int a2 = (((unsigned)(p2 - 1) < 31u) ? p2 : TRASH) * 256 + tid;
        // no-return ds_add_f32: fire-and-forget, no lgkm wait in the loop;
        // bank = tid mod 32 for all -> conflict-free
        atomicAdd(&bins[a0], sm);
        atomicAdd(&bins[a1], s0v - sm);
        atomicAdd(&bins[a2], 1.0f - s0v);
    }

    bins[0 * 256 + tid] = v0acc;
    __syncthreads();

    // merge 4 wave-lanes into tid = t (c = 0..31; trash skipped)
    for (int cell = tid; cell < 32 * 64; cell += 256) {
        const int cc = cell >> 6;               // 0..31
        const int tt = cell & 63;
        const float sum = bins[cc * 256 +   0 + tt] + bins[cc * 256 +  64 + tt]
                        + bins[cc * 256 + 128 + tt] + bins[cc * 256 + 192 + tt];
        bins[cc * 256 + tt] = sum;              // same-thread RMW, safe
    }
    __syncthreads();

    // prefix over c and coalesced store: wave w covers s in [8w, 8w+8)
    float run = bins[0 * 256 + t];              // base = value at s=0
    const int sbase = 8 * w;
    for (int cc = 1; cc < sbase; cc++) run += bins[cc * 256 + t];
    float* wsb = ws + (size_t)b * (S * T);
#pragma unroll
    for (int j = 0; j < 8; j++) {
        const int s = sbase + j;
        if (s >= 1) run += bins[s * 256 + t];
        wsb[s * T + t] = run;
    }
}

// Phase 2: out[g][i] = sum of 8 prefixed slice partials, float4-wide
// (plain stores cover the whole output -> no memset needed)
__global__ __launch_bounds__(256) void ect_reduce(
    const float4* __restrict__ ws4, float4* __restrict__ out4)
{
    const int idx = blockIdx.x * 256 + threadIdx.x;  // [0, 64*512)
    const int g   = idx >> 9;                        // 512 float4 per graph
    const int i   = idx & 511;
    float4 sum = {0.0f, 0.0f, 0.0f, 0.0f};
#pragma unroll
    for (int c = 0; c < NSPLIT; c++) {
        const float4 a = ws4[(size_t)(g * NSPLIT + c) * 512 + i];
        sum.x += a.x; sum.y += a.y; sum.z += a.z; sum.w += a.w;
    }
    out4[idx] = sum;
}

extern "C" void kernel_launch(void* const* d_in, const int* in_sizes, int n_in,
                              void* d_out, int out_size, void* d_ws, size_t ws_size,
                              hipStream_t stream) {
    const float* x     = (const float*)d_in[0];
    const float* v     = (const float*)d_in[1];
    const float* lin   = (const float*)d_in[2];
    const int*   batch = (const int*)d_in[3];
    float* out = (float*)d_out;
    float* ws  = (float*)d_ws;                   // 512 * 2048 floats = 4.2 MB

    const int n_points = in_sizes[0] / 3;

    ect_partial<<<NGRAPH * NSPLIT, 256, 0, stream>>>(x, v, lin, batch, ws, n_points);
    ect_reduce<<<NGRAPH * S * T / 4 / 256, 256, 0, stream>>>(
        (const float4*)ws, (float4*)out);
}

// Round 3
// 88.996 us; speedup vs baseline: 1.4504x; 1.4504x over previous
//
#include <hip/hip_runtime.h>

#define T      64
#define S      32
#define NGRAPH 64
#define NSPLIT 8      // slices per graph -> 512 blocks of 256 (2 blocks/CU)
#define NW     4

// R14: DENSE REGISTER accumulation. R13 post-mortem: float LDS atomicAdd
// lowered to a CAS loop (71 us, VALUBusy 5.5%); even R0's explicit RMW sat
// ~4x above the throughput floor, latency-serialized on the data-dependent
// LDS chain (ds_read->add->ds_write, lgkm-coupled with the x[] s_loads).
// Fix: keep all 32 slot accumulators in VGPRs and apply the validated
// per-node profile (0..0, sm, s0v, 1..1) with a branch-free select per
// slot. No LDS, no RMW, no data-dependent addressing in the loop ->
// pure VALU, ~206 instr/node, predicted ~12 us.
//
// Numerics: identical per-node values to the R9/R10-validated delta
// encoding (P(s) = 1 if s>ss, s0v if s==ss, sm if s==ss-1, else 0;
// third-delta approx err <= 8.2e-4). Only the summation order differs.
__global__ __launch_bounds__(256, 2) void ect_partial(
    const float* __restrict__ x, const float* __restrict__ v,
    const float* __restrict__ lin, const int* __restrict__ batch,
    float* __restrict__ ws, int n_points)
{
    __shared__ float bins[256 * 33]; // [tid][s], stride 33: bank=(tid+s)%32

    const int tid  = threadIdx.x;
    const int t    = tid & 63;       // lane == theta
    const int w    = __builtin_amdgcn_readfirstlane(tid >> 6); // wave id, SGPR
    const int b    = blockIdx.x;
    const int g    = b >> 3;         // graph
    const int c    = b & (NSPLIT - 1);

    // 32-ary ballot search (lanes<32: lower_bound(g), >=32: lower_bound(g+1))
    const int target = (t < 32) ? g : (g + 1);
    const int i32    = t & 31;
    int lo = 0;
    const int strides[3] = {2048, 64, 2};
#pragma unroll
    for (int rnd = 0; rnd < 3; rnd++) {
        const int stride = strides[rnd];
        const int idx  = lo + i32 * stride;
        const int pv   = batch[min(idx, n_points - 1)];
        const bool prd = (idx < n_points) && (pv < target);
        const unsigned long long bal = __ballot(prd);
        const int cnt = __popc((unsigned)(bal >> (t & 32)));
        lo += max(cnt - 1, 0) * stride;
    }
    if ((lo < n_points) && (batch[min(lo, n_points - 1)] < target)) lo++;
    const int gstart = __builtin_amdgcn_readfirstlane(lo);
    const int gend   = __builtin_amdgcn_readlane(lo, 32);
    const int len    = gend - gstart;
    const int n0     = gstart + (len * c) / NSPLIT;
    const int n1     = gstart + (len * (c + 1)) / NSPLIT;

    const float lin0     = lin[0];
    const float step     = lin[1] - lin0;
    const float inv_step = 1.0f / step;
    const float nl0i     = -lin0 * inv_step;
    const float K2 = (100.0f * step) * 1.4426950408889634f;   // ~10.24
    const float r  = __builtin_amdgcn_exp2f(-K2);

    const float v0 = v[0 * T + t];
    const float v1 = v[1 * T + t];
    const float v2 = v[2 * T + t];

    float acc[S];
#pragma unroll
    for (int s = 0; s < S; s++) acc[s] = 0.0f;

#pragma unroll 2
    for (int n = n0 + w; n < n1; n += NW) {     // n wave-uniform -> s_loads
        const float x0 = x[3 * n + 0];
        const float x1 = x[3 * n + 1];
        const float x2 = x[3 * n + 2];
        const float nh = fmaf(x0, v0, fmaf(x1, v1, x2 * v2));
        const float f  = fmaf(nh, inv_step, nl0i);
        const float fs = ceilf(f);
        const int   ss = (int)fs;
        const float e0 = __builtin_amdgcn_exp2f(fmaf(K2, f - fs, K2)); // (1,e^d]
        const float e1 = e0 * r;                                        // (r,1]
        const float sm  = __builtin_amdgcn_rcpf(1.0f + e0);
        const float s0v = __builtin_amdgcn_rcpf(1.0f + e1);
        // P(s): 1 for s>ss, s0v at s==ss, sm at s==ss-1, 0 below.
        // (ss<=-1 -> all 1; ss>=33 -> all 0; boundary cases match R0:
        //  ss==32 -> slot31 gets sm; ss==31 -> slot31 gets s0v.)
#pragma unroll
        for (int s = 0; s < S; s++) {
            float pc = (ss < s) ? 1.0f : 0.0f;
            pc = (ss == s)     ? s0v : pc;
            pc = (ss == s + 1) ? sm  : pc;
            acc[s] += pc;
        }
    }

    // registers -> LDS (padded stride 33: 2 lanes/bank = free)
#pragma unroll
    for (int s = 0; s < S; s++) bins[tid * 33 + s] = acc[s];
    __syncthreads();

    // merge 4 waves and store coalesced: pass p, thread tid -> (s, t)
    float* wsb = ws + (size_t)b * (S * T);
#pragma unroll
    for (int pass = 0; pass < 8; pass++) {
        const int s  = (tid >> 6) + 4 * pass;   // 0..31
        const int tt = tid & 63;
        const float sum = bins[(  0 + tt) * 33 + s] + bins[( 64 + tt) * 33 + s]
                        + bins[(128 + tt) * 33 + s] + bins[(192 + tt) * 33 + s];
        wsb[s * T + tt] = sum;                  // contiguous per wave
    }
}

// Phase 2: out[g][i] = sum of 8 slice partials, float4-wide
// (plain stores cover the whole output -> no memset needed)
__global__ __launch_bounds__(256) void ect_reduce(
    const float4* __restrict__ ws4, float4* __restrict__ out4)
{
    const int idx = blockIdx.x * 256 + threadIdx.x;  // [0, 64*512)
    const int g   = idx >> 9;                        // 512 float4 per graph
    const int i   = idx & 511;
    float4 sum = {0.0f, 0.0f, 0.0f, 0.0f};
#pragma unroll
    for (int c = 0; c < NSPLIT; c++) {
        const float4 a = ws4[(size_t)(g * NSPLIT + c) * 512 + i];
        sum.x += a.x; sum.y += a.y; sum.z += a.z; sum.w += a.w;
    }
    out4[idx] = sum;
}

extern "C" void kernel_launch(void* const* d_in, const int* in_sizes, int n_in,
                              void* d_out, int out_size, void* d_ws, size_t ws_size,
                              hipStream_t stream) {
    const float* x     = (const float*)d_in[0];
    const float* v     = (const float*)d_in[1];
    const float* lin   = (const float*)d_in[2];
    const int*   batch = (const int*)d_in[3];
    float* out = (float*)d_out;
    float* ws  = (float*)d_ws;                   // 512 * 2048 floats = 4.2 MB

    const int n_points = in_sizes[0] / 3;

    ect_partial<<<NGRAPH * NSPLIT, 256, 0, stream>>>(x, v, lin, batch, ws, n_points);
    ect_reduce<<<NGRAPH * S * T / 4 / 256, 256, 0, stream>>>(
        (const float4*)ws, (float4*)out);
}

// Round 4
// 71.685 us; speedup vs baseline: 1.8006x; 1.2415x over previous
//
#include <hip/hip_runtime.h>

#define T      64
#define S      32
#define NGRAPH 64
#define NSPLIT 16     // slices per graph -> 1024 blocks of 256 (4 blocks/CU)
#define NW     4
#define TRASH  32     // row 32 is never read (valid delta rows are 1..31)
#define XCAP   170    // staged-node capacity (512 dwords of x_lds)

// R15: back to the R0 sparse delta RMW (R14 dense-register was 2x worse:
// 7 VALU x 32 slots/node > 20 VALU + 6 DS/node; R13 fp LDS atomicAdd was a
// CAS loop). R0's 16.4 us vs ~3 us floor was latency: (a) cold wave-uniform
// x s_loads (~900 cyc each, poison fill evicts L2/L3), (b) 2 waves/SIMD
// occupancy. Fix: cooperative coalesced staging of the slice's x into LDS
// (one overlapped HBM round trip, then uniform-addr broadcast ds_reads),
// and NSPLIT=16 -> 4 blocks/CU = 4 waves/SIMD.
//
// bins TRANSPOSED: bins[c*256 + tid] -> bank = tid mod 32, independent of
// the data-dependent slot c; conflict-free by construction.
// Numerics (R9/R10-validated, absmax 4.0): per (node,theta) profile is
// 0..0, sm, s0, ~1..1; 3 deltas at slots ss-1, ss, ss+1 (third ~ 1-s0v,
// err <= 8.2e-4); slots <= 0 fold into base register; slots >= 32 -> trash.
__global__ __launch_bounds__(256, 4) void ect_partial(
    const float* __restrict__ x, const float* __restrict__ v,
    const float* __restrict__ lin, const int* __restrict__ batch,
    float* __restrict__ ws, int n_points)
{
    __shared__ float bins[33 * 256]; // [c][tid]: c=0 base, 1..31 deltas, 32 trash
    __shared__ float x_lds[512];     // staged x for this slice (<=170 nodes)

    const int tid  = threadIdx.x;
    const int t    = tid & 63;       // lane == theta
    const int w    = __builtin_amdgcn_readfirstlane(tid >> 6); // wave id, SGPR
    const int b    = blockIdx.x;
    const int g    = b >> 4;         // graph
    const int c    = b & (NSPLIT - 1);

    {   // vectorized zero-init of rows 0..32: 2112 float4
        const float4 z4 = {0.0f, 0.0f, 0.0f, 0.0f};
        float4* b4 = (float4*)bins;
        for (int i = tid; i < 33 * 256 / 4; i += 256) b4[i] = z4;
    }

    // 32-ary ballot search (lanes<32: lower_bound(g), >=32: lower_bound(g+1))
    const int target = (t < 32) ? g : (g + 1);
    const int i32    = t & 31;
    int lo = 0;
    const int strides[3] = {2048, 64, 2};
#pragma unroll
    for (int rnd = 0; rnd < 3; rnd++) {
        const int stride = strides[rnd];
        const int idx  = lo + i32 * stride;
        const int pv   = batch[min(idx, n_points - 1)];
        const bool prd = (idx < n_points) && (pv < target);
        const unsigned long long bal = __ballot(prd);
        const int cnt = __popc((unsigned)(bal >> (t & 32)));
        lo += max(cnt - 1, 0) * stride;
    }
    if ((lo < n_points) && (batch[min(lo, n_points - 1)] < target)) lo++;
    const int gstart = __builtin_amdgcn_readfirstlane(lo);
    const int gend   = __builtin_amdgcn_readlane(lo, 32);
    const int len    = gend - gstart;
    const int n0     = gstart + (len * c) / NSPLIT;
    const int n1     = gstart + (len * (c + 1)) / NSPLIT;
    const int sliceLen = n1 - n0;

    {   // coalesced staging: x[3*n0 .. 3*n1) -> x_lds (<=2 dwords/thread)
        const int base3 = 3 * n0;
        const int limit = 3 * min(sliceLen, XCAP);
        for (int p = tid; p < limit; p += 256)
            x_lds[p] = x[base3 + p];     // base3+p < 3*n1 <= 3*n_points
    }

    const float lin0     = lin[0];
    const float step     = lin[1] - lin0;
    const float inv_step = 1.0f / step;
    const float nl0i     = -lin0 * inv_step;
    const float K2 = (100.0f * step) * 1.4426950408889634f;   // ~10.24
    const float r  = __builtin_amdgcn_exp2f(-K2);

    const float v0 = v[0 * T + t];
    const float v1 = v[1 * T + t];
    const float v2 = v[2 * T + t];

    float v0acc = 0.0f;                 // profile value at s=0
    __syncthreads();                    // init + staging complete

#define ECT_BODY(X0, X1, X2)                                                  \
    {                                                                         \
        const float nh = fmaf((X0), v0, fmaf((X1), v1, (X2) * v2));           \
        const float f  = fmaf(nh, inv_step, nl0i);                            \
        const float fs = ceilf(f);                                            \
        const int   ss = (int)fs;                                             \
        const float e0 = __builtin_amdgcn_exp2f(fmaf(K2, f - fs, K2));        \
        const float e1 = e0 * r;                                              \
        const float sm  = __builtin_amdgcn_rcpf(1.0f + e0);                   \
        const float s0v = __builtin_amdgcn_rcpf(1.0f + e1);                   \
        v0acc += (ss <= -1) ? 1.0f : (ss == 0 ? s0v : (ss == 1 ? sm : 0.0f)); \
        const int p0 = ss - 1, p1 = ss, p2 = ss + 1;                          \
        const int a0 = (((unsigned)(p0 - 1) < 31u) ? p0 : TRASH) * 256 + tid; \
        const int a1 = (((unsigned)(p1 - 1) < 31u) ? p1 : TRASH) * 256 + tid; \
        const int a2 = (((unsigned)(p2 - 1) < 31u) ? p2 : TRASH) * 256 + tid; \
        const float r0 = bins[a0], r1 = bins[a1], r2 = bins[a2];              \
        bins[a0] = r0 + sm;                                                   \
        bins[a1] = r1 + (s0v - sm);                                           \
        bins[a2] = r2 + (1.0f - s0v);                                         \
    }

    if (sliceLen <= XCAP) {             // staged path (always, in practice)
#pragma unroll 4
        for (int n = n0 + w; n < n1; n += NW) {
            const int li3 = 3 * (n - n0);
            const float x0 = x_lds[li3 + 0];   // uniform addr -> broadcast
            const float x1 = x_lds[li3 + 1];
            const float x2 = x_lds[li3 + 2];
            ECT_BODY(x0, x1, x2)
        }
    } else {                            // safety fallback: direct global
#pragma unroll 2
        for (int n = n0 + w; n < n1; n += NW) {
            const float x0 = x[3 * n + 0];
            const float x1 = x[3 * n + 1];
            const float x2 = x[3 * n + 2];
            ECT_BODY(x0, x1, x2)
        }
    }
#undef ECT_BODY

    bins[0 * 256 + tid] = v0acc;
    __syncthreads();

    // merge 4 wave-lanes into tid = t (c = 0..31; trash skipped)
    for (int cell = tid; cell < 32 * 64; cell += 256) {
        const int cc = cell >> 6;               // 0..31
        const int tt = cell & 63;
        const float sum = bins[cc * 256 +   0 + tt] + bins[cc * 256 +  64 + tt]
                        + bins[cc * 256 + 128 + tt] + bins[cc * 256 + 192 + tt];
        bins[cc * 256 + tt] = sum;              // same-thread RMW, safe
    }
    __syncthreads();

    // prefix over c and coalesced store: wave w covers s in [8w, 8w+8)
    float run = bins[0 * 256 + t];              // base = value at s=0
    const int sbase = 8 * w;
    for (int cc = 1; cc < sbase; cc++) run += bins[cc * 256 + t];
    float* wsb = ws + (size_t)b * (S * T);
#pragma unroll
    for (int j = 0; j < 8; j++) {
        const int s = sbase + j;
        if (s >= 1) run += bins[s * 256 + t];
        wsb[s * T + t] = run;
    }
}

// Phase 2: out[g][i] = sum of 16 prefixed slice partials, float4-wide
// (plain stores cover the whole output -> no memset needed)
__global__ __launch_bounds__(256) void ect_reduce(
    const float4* __restrict__ ws4, float4* __restrict__ out4)
{
    const int idx = blockIdx.x * 256 + threadIdx.x;  // [0, 64*512)
    const int g   = idx >> 9;                        // 512 float4 per graph
    const int i   = idx & 511;
    float4 sum = {0.0f, 0.0f, 0.0f, 0.0f};
#pragma unroll
    for (int c = 0; c < NSPLIT; c++) {
        const float4 a = ws4[(size_t)(g * NSPLIT + c) * 512 + i];
        sum.x += a.x; sum.y += a.y; sum.z += a.z; sum.w += a.w;
    }
    out4[idx] = sum;
}

extern "C" void kernel_launch(void* const* d_in, const int* in_sizes, int n_in,
                              void* d_out, int out_size, void* d_ws, size_t ws_size,
                              hipStream_t stream) {
    const float* x     = (const float*)d_in[0];
    const float* v     = (const float*)d_in[1];
    const float* lin   = (const float*)d_in[2];
    const int*   batch = (const int*)d_in[3];
    float* out = (float*)d_out;
    float* ws  = (float*)d_ws;                   // 1024 * 2048 floats = 8.4 MB

    const int n_points = in_sizes[0] / 3;

    ect_partial<<<NGRAPH * NSPLIT, 256, 0, stream>>>(x, v, lin, batch, ws, n_points);
    ect_reduce<<<NGRAPH * S * T / 4 / 256, 256, 0, stream>>>(
        (const float4*)ws, (float4*)out);
}